// Round 1
// baseline (557.976 us; speedup 1.0000x reference)
//
#include <hip/hip_runtime.h>

// RelativeMultiHeadAttention (B=8, T=2048, D_MODEL=1024, H=16, D_HEAD=64)
// Pipeline:
//   1) transpose+convert 5 weight matrices to bf16 [N][K] in ws
//   2) 4x bf16-MFMA GEMMs: q,k,v = inputs@W+b ; p = pos@Wp   (f32 A, bf16 out)
//   3) attention kernel: per (b,t) 16x16 scores (+rel-shifted pos scores),
//      softmax, ctx; writes ctx in output-GEMM-ready permuted layout (bf16)
//   4) final GEMM: out = ctx@Wo + bo (f32 out)
//
// rel_shift reduces to: shifted[m] = pos_score[f=m+8 over flat (b*(T+1)+t)]:
//   b_s = f/2049, t_s = f%2049; zero block if t_s==0 else source (b_s, t_s-1).

typedef __attribute__((ext_vector_type(8))) short short8;
typedef __attribute__((ext_vector_type(4))) float f32x4;

__device__ __forceinline__ ushort f2bf(float f) {
    unsigned u = __float_as_uint(f);
    u += 0x7FFFu + ((u >> 16) & 1u);   // round-to-nearest-even
    return (ushort)(u >> 16);
}
__device__ __forceinline__ float bf2f(ushort u) {
    return __uint_as_float(((unsigned)u) << 16);
}

// ---------------- Wt[n][k] = bf16(W[k][n]) ----------------
__global__ __launch_bounds__(256)
void transpose_convert_k(const float* __restrict__ W, ushort* __restrict__ Wt, int K, int N)
{
    __shared__ float tile[32][33];
    const int tx = threadIdx.x & 31;
    const int ty = threadIdx.x >> 5;   // 0..7
    const int n0 = blockIdx.x * 32;
    const int k0 = blockIdx.y * 32;
#pragma unroll
    for (int i = 0; i < 4; ++i)
        tile[ty + i * 8][tx] = W[(size_t)(k0 + ty + i * 8) * N + n0 + tx];
    __syncthreads();
#pragma unroll
    for (int i = 0; i < 4; ++i)
        Wt[(size_t)(n0 + ty + i * 8) * K + k0 + tx] = f2bf(tile[tx][ty + i * 8]);
}

// ---------------- GEMM: C[M][N] = A[M][K] @ Bt[N][K]^T (+bias) ----------------
#define BM 128
#define BN 128
#define BKK 32
#define LDT 56   // padded LDS K-stride (bf16 elems): 112B = 16B-aligned, frag reads conflict-free

template<int A_BF16, int HAS_BIAS, int OUT_BF16>
__global__ __launch_bounds__(256)
void gemm_k(const void* __restrict__ Av, const ushort* __restrict__ Bt,
            const float* __restrict__ bias, void* __restrict__ Cv,
            int M, int N, int K)
{
    __shared__ ushort As[BM * LDT];
    __shared__ ushort Bs[BN * LDT];
    const int tid  = threadIdx.x;
    const int lane = tid & 63;
    const int wave = tid >> 6;
    const int bm = blockIdx.y * BM;
    const int bn = blockIdx.x * BN;
    const int wm = (wave >> 1) * 64;
    const int wn = (wave & 1) * 64;
    const int lr = lane & 15;          // fragment row/col within 16
    const int kq = (lane >> 4) * 8;    // fragment k offset
    const int sr = tid >> 2;           // staging row 0..63
    const int sc = (tid & 3) * 8;      // staging k offset {0,8,16,24}

    f32x4 acc[4][4];
#pragma unroll
    for (int i = 0; i < 4; ++i)
#pragma unroll
        for (int j = 0; j < 4; ++j)
            acc[i][j] = (f32x4){0.f, 0.f, 0.f, 0.f};

    for (int kt = 0; kt < K; kt += BKK) {
#pragma unroll
        for (int p = 0; p < 2; ++p) {
            const int r = p * 64 + sr;
            short8 av;
            if (A_BF16) {
                av = *(const short8*)((const ushort*)Av + (size_t)(bm + r) * K + kt + sc);
            } else {
                const float* s = (const float*)Av + (size_t)(bm + r) * K + kt + sc;
                float4 f0 = *(const float4*)s;
                float4 f1 = *(const float4*)(s + 4);
                av = (short8){(short)f2bf(f0.x), (short)f2bf(f0.y), (short)f2bf(f0.z), (short)f2bf(f0.w),
                              (short)f2bf(f1.x), (short)f2bf(f1.y), (short)f2bf(f1.z), (short)f2bf(f1.w)};
            }
            *(short8*)&As[r * LDT + sc] = av;
            short8 bv8 = *(const short8*)(Bt + (size_t)(bn + r) * K + kt + sc);
            *(short8*)&Bs[r * LDT + sc] = bv8;
        }
        __syncthreads();

        short8 af[4], bf[4];
#pragma unroll
        for (int i = 0; i < 4; ++i)
            af[i] = *(const short8*)&As[(wm + i * 16 + lr) * LDT + kq];
#pragma unroll
        for (int i = 0; i < 4; ++i)
            bf[i] = *(const short8*)&Bs[(wn + i * 16 + lr) * LDT + kq];
#pragma unroll
        for (int i = 0; i < 4; ++i)
#pragma unroll
            for (int j = 0; j < 4; ++j)
                acc[i][j] = __builtin_amdgcn_mfma_f32_16x16x32_bf16(af[i], bf[j], acc[i][j], 0, 0, 0);
        __syncthreads();
    }

    // epilogue: C/D layout col=lane&15, row=(lane>>4)*4+reg
    const int cr = (lane >> 4) * 4;
    const int cc = lane & 15;
#pragma unroll
    for (int i = 0; i < 4; ++i) {
#pragma unroll
        for (int j = 0; j < 4; ++j) {
#pragma unroll
            for (int r = 0; r < 4; ++r) {
                const int row = bm + wm + i * 16 + cr + r;
                const int col = bn + wn + j * 16 + cc;
                float v = acc[i][j][r];
                if (HAS_BIAS) v += bias[col];
                if (OUT_BF16) ((ushort*)Cv)[(size_t)row * N + col] = f2bf(v);
                else          ((float*)Cv)[(size_t)row * N + col] = v;
            }
        }
    }
}

// ---------------- per-(b,t) attention ----------------
__global__ __launch_bounds__(256)
void attn_k(const ushort* __restrict__ qb, const ushort* __restrict__ kb,
            const ushort* __restrict__ vbuf, const ushort* __restrict__ pbuf,
            const float* __restrict__ ubias, const float* __restrict__ vbias,
            const int* __restrict__ masks, ushort* __restrict__ ctx)
{
    __shared__ float qu[16][65];   // q(m)+u_bias
    __shared__ float kk[16][65];
    __shared__ float vv[16][65];
    __shared__ float qv[16][65];   // q(mp)+v_bias (rel-shift source)
    __shared__ float pp[16][65];
    __shared__ float at[16][16];

    const int m  = blockIdx.x;         // b2*T + t2
    const int b2 = m >> 11;
    const int t2 = m & 2047;
    const int f  = m + 8;              // rel-shift: flat block index + B
    const int bs = f / 2049;
    const int ts = f - bs * 2049;
    const bool haspos = (ts != 0);     // ts==0 -> zero pad row
    const int mp = bs * 2048 + ts - 1;

    const int tid = threadIdx.x;
    const int e = tid * 4;
    const int h = e >> 6;
    const int d = e & 63;

    {
        ushort4 a = *(const ushort4*)(qb   + (size_t)m * 1024 + e);
        ushort4 b = *(const ushort4*)(kb   + (size_t)m * 1024 + e);
        ushort4 c = *(const ushort4*)(vbuf + (size_t)m * 1024 + e);
        float4 uu = *(const float4*)(ubias + e);
        qu[h][d + 0] = bf2f(a.x) + uu.x;
        qu[h][d + 1] = bf2f(a.y) + uu.y;
        qu[h][d + 2] = bf2f(a.z) + uu.z;
        qu[h][d + 3] = bf2f(a.w) + uu.w;
        kk[h][d + 0] = bf2f(b.x);
        kk[h][d + 1] = bf2f(b.y);
        kk[h][d + 2] = bf2f(b.z);
        kk[h][d + 3] = bf2f(b.w);
        vv[h][d + 0] = bf2f(c.x);
        vv[h][d + 1] = bf2f(c.y);
        vv[h][d + 2] = bf2f(c.w);  // placeholder, fixed below
        vv[h][d + 2] = bf2f(c.z);
        vv[h][d + 3] = bf2f(c.w);
        if (haspos) {
            ushort4 qq = *(const ushort4*)(qb   + (size_t)mp * 1024 + e);
            ushort4 pq = *(const ushort4*)(pbuf + (size_t)mp * 1024 + e);
            float4 vv4 = *(const float4*)(vbias + e);
            qv[h][d + 0] = bf2f(qq.x) + vv4.x;
            qv[h][d + 1] = bf2f(qq.y) + vv4.y;
            qv[h][d + 2] = bf2f(qq.z) + vv4.z;
            qv[h][d + 3] = bf2f(qq.w) + vv4.w;
            pp[h][d + 0] = bf2f(pq.x);
            pp[h][d + 1] = bf2f(pq.y);
            pp[h][d + 2] = bf2f(pq.z);
            pp[h][d + 3] = bf2f(pq.w);
        } else {
            qv[h][d + 0] = 0.f; qv[h][d + 1] = 0.f; qv[h][d + 2] = 0.f; qv[h][d + 3] = 0.f;
            pp[h][d + 0] = 0.f; pp[h][d + 1] = 0.f; pp[h][d + 2] = 0.f; pp[h][d + 3] = 0.f;
        }
    }
    __syncthreads();

    const int sh = tid >> 4;   // score row h
    const int sk = tid & 15;   // score col k'
    float cs = 0.f, ps = 0.f;
#pragma unroll 8
    for (int dd = 0; dd < 64; ++dd) {
        cs += qu[sh][dd] * kk[sk][dd];
        ps += qv[sh][dd] * pp[sk][dd];
    }
    float score = (cs + ps) * 0.03125f;   // /sqrt(1024)
    score = (masks[m] != 0) ? score : 1e-9f;

    // softmax over sk within contiguous 16-lane groups
    float mx = score;
#pragma unroll
    for (int o = 8; o; o >>= 1) mx = fmaxf(mx, __shfl_xor(mx, o, 64));
    float ex = __expf(score - mx);
    float sum = ex;
#pragma unroll
    for (int o = 8; o; o >>= 1) sum += __shfl_xor(sum, o, 64);
    at[sh][sk] = ex / sum;
    __syncthreads();

    // ctx[h][d] = sum_k at[h][k]*v[k][d]; write in output-GEMM layout:
    // row = b2*2048 + h*128 + t2/16, col = (t2%16)*64 + d
#pragma unroll
    for (int j = 0; j < 4; ++j) {
        const int idx = tid + j * 256;
        const int hh = idx >> 6;
        const int dd2 = idx & 63;
        float s = 0.f;
#pragma unroll
        for (int k2 = 0; k2 < 16; ++k2)
            s += at[hh][k2] * vv[k2][dd2];
        const size_t orow = (size_t)b2 * 2048 + hh * 128 + (t2 >> 4);
        ctx[orow * 1024 + (t2 & 15) * 64 + dd2] = f2bf(s);
    }
}

extern "C" void kernel_launch(void* const* d_in, const int* in_sizes, int n_in,
                              void* d_out, int out_size, void* d_ws, size_t ws_size,
                              hipStream_t stream)
{
    (void)in_sizes; (void)n_in; (void)out_size; (void)ws_size;
    const float* inputs = (const float*)d_in[0];
    const float* pos    = (const float*)d_in[1];
    const int*   masks  = (const int*)d_in[2];
    const float* Wq = (const float*)d_in[3];
    const float* bq = (const float*)d_in[4];
    const float* Wk = (const float*)d_in[5];
    const float* bk = (const float*)d_in[6];
    const float* Wv = (const float*)d_in[7];
    const float* bv = (const float*)d_in[8];
    const float* Wp = (const float*)d_in[9];
    const float* Wo = (const float*)d_in[10];
    const float* bo = (const float*)d_in[11];
    const float* ub = (const float*)d_in[12];
    const float* vb = (const float*)d_in[13];

    char* ws = (char*)d_ws;
    const size_t WT_SZ = (size_t)1024 * 1024 * 2;       // 2MB per transposed weight
    const size_t Q_SZ  = (size_t)16384 * 1024 * 2;      // 32MB per activation
    ushort* WqT = (ushort*)(ws + 0 * WT_SZ);
    ushort* WkT = (ushort*)(ws + 1 * WT_SZ);
    ushort* WvT = (ushort*)(ws + 2 * WT_SZ);
    ushort* WpT = (ushort*)(ws + 3 * WT_SZ);
    ushort* WoT = (ushort*)(ws + 4 * WT_SZ);
    ushort* qbuf = (ushort*)(ws + 5 * WT_SZ);
    ushort* kbuf = (ushort*)(ws + 5 * WT_SZ + 1 * Q_SZ);
    ushort* vbuf = (ushort*)(ws + 5 * WT_SZ + 2 * Q_SZ);
    ushort* pbuf = (ushort*)(ws + 5 * WT_SZ + 3 * Q_SZ);
    ushort* cbuf = (ushort*)(ws + 5 * WT_SZ + 4 * Q_SZ);

    dim3 blk(256);
    dim3 tgrid(32, 32);
    transpose_convert_k<<<tgrid, blk, 0, stream>>>(Wq, WqT, 1024, 1024);
    transpose_convert_k<<<tgrid, blk, 0, stream>>>(Wk, WkT, 1024, 1024);
    transpose_convert_k<<<tgrid, blk, 0, stream>>>(Wv, WvT, 1024, 1024);
    transpose_convert_k<<<tgrid, blk, 0, stream>>>(Wp, WpT, 1024, 1024);
    transpose_convert_k<<<tgrid, blk, 0, stream>>>(Wo, WoT, 1024, 1024);

    dim3 ggrid(1024 / BN, 16384 / BM);   // (8, 128)
    gemm_k<0, 1, 1><<<ggrid, blk, 0, stream>>>(inputs, WqT, bq, qbuf, 16384, 1024, 1024);
    gemm_k<0, 1, 1><<<ggrid, blk, 0, stream>>>(inputs, WkT, bk, kbuf, 16384, 1024, 1024);
    gemm_k<0, 1, 1><<<ggrid, blk, 0, stream>>>(inputs, WvT, bv, vbuf, 16384, 1024, 1024);
    gemm_k<0, 0, 1><<<ggrid, blk, 0, stream>>>(pos,    WpT, nullptr, pbuf, 16384, 1024, 1024);

    attn_k<<<dim3(16384), blk, 0, stream>>>(qbuf, kbuf, vbuf, pbuf, ub, vb, masks, cbuf);

    gemm_k<1, 1, 0><<<ggrid, blk, 0, stream>>>(cbuf, WoT, bo, d_out, 16384, 1024, 1024);
}

// Round 2
// 407.449 us; speedup vs baseline: 1.3694x; 1.3694x over previous
//
#include <hip/hip_runtime.h>

// RelativeMultiHeadAttention (B=8, T=2048, D_MODEL=1024, H=16, D_HEAD=64)
// Round 2: m97-structure GEMM (global_load_lds w=16, linear LDS, 2-barrier),
// fused QKV GEMM (N=3072), f32->bf16 pre-convert of activations.
//
// rel_shift: shifted[m] = pos_score[f=m+8 over flat (b*(T+1)+t)]:
//   b_s = f/2049, t_s = f%2049; zero block if t_s==0 else source (b_s, t_s-1).

typedef __attribute__((ext_vector_type(8))) short short8;
typedef __attribute__((ext_vector_type(4))) float f32x4;

__device__ __forceinline__ ushort f2bf(float f) {
    unsigned u = __float_as_uint(f);
    u += 0x7FFFu + ((u >> 16) & 1u);   // round-to-nearest-even
    return (ushort)(u >> 16);
}
__device__ __forceinline__ float bf2f(ushort u) {
    return __uint_as_float(((unsigned)u) << 16);
}

typedef const unsigned int __attribute__((address_space(1)))* gas_t;
typedef unsigned int __attribute__((address_space(3)))* las_t;
__device__ __forceinline__ void gl_lds16(const ushort* g, ushort* l) {
    // direct global->LDS, 16B per lane; LDS dest = wave-uniform base + lane*16
    __builtin_amdgcn_global_load_lds((gas_t)g, (las_t)l, 16, 0, 0);
}

// ---------------- f32 -> bf16 convert (8 elems/thread) ----------------
__global__ __launch_bounds__(256)
void conv_bf16_k(const float* __restrict__ in, ushort* __restrict__ out)
{
    const size_t i = ((size_t)blockIdx.x * 256 + threadIdx.x) * 8;
    float4 a = *(const float4*)(in + i);
    float4 b = *(const float4*)(in + i + 4);
    short8 o = {(short)f2bf(a.x), (short)f2bf(a.y), (short)f2bf(a.z), (short)f2bf(a.w),
                (short)f2bf(b.x), (short)f2bf(b.y), (short)f2bf(b.z), (short)f2bf(b.w)};
    *(short8*)(out + i) = o;
}

// ---------------- Wt[n][k] = bf16(W[k][n]) ----------------
__global__ __launch_bounds__(256)
void transpose_convert_k(const float* __restrict__ W, ushort* __restrict__ Wt, int K, int N)
{
    __shared__ float tile[32][33];
    const int tx = threadIdx.x & 31;
    const int ty = threadIdx.x >> 5;   // 0..7
    const int n0 = blockIdx.x * 32;
    const int k0 = blockIdx.y * 32;
#pragma unroll
    for (int i = 0; i < 4; ++i)
        tile[ty + i * 8][tx] = W[(size_t)(k0 + ty + i * 8) * N + n0 + tx];
    __syncthreads();
#pragma unroll
    for (int i = 0; i < 4; ++i)
        Wt[(size_t)(n0 + ty + i * 8) * K + k0 + tx] = f2bf(tile[tx][ty + i * 8]);
}

// ---------------- bias concat [bq;bk;bv] ----------------
__global__ __launch_bounds__(256)
void bias_concat_k(const float* __restrict__ b0, const float* __restrict__ b1,
                   const float* __restrict__ b2, float* __restrict__ out)
{
    const int i = blockIdx.x * 256 + threadIdx.x;   // 0..3071
    const int s = i >> 10;
    const int j = i & 1023;
    out[i] = (s == 0) ? b0[j] : (s == 1) ? b1[j] : b2[j];
}

// ---------------- m97-structure GEMM: C[M][N] = A[M][K] @ Bt[N][K]^T ----------------
// BM=BN=128, BK=32, 256 threads (4 waves, 2x2 of 64x64), linear LDS [128][32] bf16.
template<int HAS_BIAS, int OUT_BF16>
__global__ __launch_bounds__(256)
void gemm2_k(const ushort* __restrict__ A, const ushort* __restrict__ Bt,
             const float* __restrict__ bias, void* __restrict__ Cv,
             int N, int K)
{
    __shared__ ushort As[128 * 32];   // 8KB
    __shared__ ushort Bs[128 * 32];   // 8KB
    const int tid  = threadIdx.x;
    const int lane = tid & 63;
    const int wave = tid >> 6;
    const int bm = blockIdx.y * 128;
    const int bn = blockIdx.x * 128;
    const int wm = (wave >> 1) * 64;
    const int wn = (wave & 1) * 64;
    const int lr = lane & 15;          // fragment row
    const int kq = (lane >> 4) * 8;    // fragment k offset

    // staging: 8 x 1KB instructions per operand; instr i covers LDS rows 16i..16i+15
    // i = wave*2 + j  (j in {0,1}); lane covers row i*16 + lane/4, col (lane&3)*8
    const int sr  = lane >> 2;
    const int scb = (lane & 3) * 8;
    const ushort* ag0 = A  + (size_t)(bm + wave * 32 + sr) * K + scb;
    const ushort* ag1 = ag0 + (size_t)16 * K;
    const ushort* bg0 = Bt + (size_t)(bn + wave * 32 + sr) * K + scb;
    const ushort* bg1 = bg0 + (size_t)16 * K;
    ushort* as0 = &As[(wave * 2 + 0) * 512];
    ushort* as1 = &As[(wave * 2 + 1) * 512];
    ushort* bs0 = &Bs[(wave * 2 + 0) * 512];
    ushort* bs1 = &Bs[(wave * 2 + 1) * 512];

    f32x4 acc[4][4];
#pragma unroll
    for (int i = 0; i < 4; ++i)
#pragma unroll
        for (int j = 0; j < 4; ++j)
            acc[i][j] = (f32x4){0.f, 0.f, 0.f, 0.f};

    for (int kt = 0; kt < K; kt += 32) {
        gl_lds16(ag0 + kt, as0);
        gl_lds16(ag1 + kt, as1);
        gl_lds16(bg0 + kt, bs0);
        gl_lds16(bg1 + kt, bs1);
        __syncthreads();   // compiler drains vmcnt before barrier

        short8 af[4], bf[4];
#pragma unroll
        for (int i = 0; i < 4; ++i)
            af[i] = *(const short8*)&As[(wm + i * 16 + lr) * 32 + kq];
#pragma unroll
        for (int i = 0; i < 4; ++i)
            bf[i] = *(const short8*)&Bs[(wn + i * 16 + lr) * 32 + kq];
#pragma unroll
        for (int i = 0; i < 4; ++i)
#pragma unroll
            for (int j = 0; j < 4; ++j)
                acc[i][j] = __builtin_amdgcn_mfma_f32_16x16x32_bf16(af[i], bf[j], acc[i][j], 0, 0, 0);
        __syncthreads();   // protect LDS before next iteration's overwrite
    }

    // epilogue: C/D layout col=lane&15, row=(lane>>4)*4+reg
    const int cr = (lane >> 4) * 4;
    const int cc = lane & 15;
#pragma unroll
    for (int i = 0; i < 4; ++i) {
#pragma unroll
        for (int j = 0; j < 4; ++j) {
            const int col = bn + wn + j * 16 + cc;
            float bv = HAS_BIAS ? bias[col] : 0.f;
#pragma unroll
            for (int r = 0; r < 4; ++r) {
                const int row = bm + wm + i * 16 + cr + r;
                float v = acc[i][j][r] + bv;
                if (OUT_BF16) ((ushort*)Cv)[(size_t)row * N + col] = f2bf(v);
                else          ((float*)Cv)[(size_t)row * N + col] = v;
            }
        }
    }
}

// ---------------- per-(b,t) attention ----------------
// qkv: [16384][3072] (q|k|v per timestep), pbuf: [16384][1024]
__global__ __launch_bounds__(256)
void attn_k(const ushort* __restrict__ qkv, const ushort* __restrict__ pbuf,
            const float* __restrict__ ubias, const float* __restrict__ vbias,
            const int* __restrict__ masks, ushort* __restrict__ ctx)
{
    __shared__ float qu[16][65];   // q(m)+u_bias
    __shared__ float kk[16][65];
    __shared__ float vv[16][65];
    __shared__ float qv[16][65];   // q(mp)+v_bias (rel-shift source)
    __shared__ float pp[16][65];
    __shared__ float at[16][16];

    const int m  = blockIdx.x;         // b2*T + t2
    const int b2 = m >> 11;
    const int t2 = m & 2047;
    const int f  = m + 8;              // rel-shift: flat block index + B
    const int bs = f / 2049;
    const int ts = f - bs * 2049;
    const bool haspos = (ts != 0);     // ts==0 -> zero pad row
    const int mp = bs * 2048 + ts - 1;

    const int tid = threadIdx.x;
    const int e = tid * 4;
    const int h = e >> 6;
    const int d = e & 63;

    {
        const ushort* base = qkv + (size_t)m * 3072;
        ushort4 a = *(const ushort4*)(base + e);
        ushort4 b = *(const ushort4*)(base + 1024 + e);
        ushort4 c = *(const ushort4*)(base + 2048 + e);
        float4 uu = *(const float4*)(ubias + e);
        qu[h][d + 0] = bf2f(a.x) + uu.x;
        qu[h][d + 1] = bf2f(a.y) + uu.y;
        qu[h][d + 2] = bf2f(a.z) + uu.z;
        qu[h][d + 3] = bf2f(a.w) + uu.w;
        kk[h][d + 0] = bf2f(b.x);
        kk[h][d + 1] = bf2f(b.y);
        kk[h][d + 2] = bf2f(b.z);
        kk[h][d + 3] = bf2f(b.w);
        vv[h][d + 0] = bf2f(c.x);
        vv[h][d + 1] = bf2f(c.y);
        vv[h][d + 2] = bf2f(c.z);
        vv[h][d + 3] = bf2f(c.w);
        if (haspos) {
            ushort4 qq = *(const ushort4*)(qkv + (size_t)mp * 3072 + e);
            ushort4 pq = *(const ushort4*)(pbuf + (size_t)mp * 1024 + e);
            float4 vv4 = *(const float4*)(vbias + e);
            qv[h][d + 0] = bf2f(qq.x) + vv4.x;
            qv[h][d + 1] = bf2f(qq.y) + vv4.y;
            qv[h][d + 2] = bf2f(qq.z) + vv4.z;
            qv[h][d + 3] = bf2f(qq.w) + vv4.w;
            pp[h][d + 0] = bf2f(pq.x);
            pp[h][d + 1] = bf2f(pq.y);
            pp[h][d + 2] = bf2f(pq.z);
            pp[h][d + 3] = bf2f(pq.w);
        } else {
            qv[h][d + 0] = 0.f; qv[h][d + 1] = 0.f; qv[h][d + 2] = 0.f; qv[h][d + 3] = 0.f;
            pp[h][d + 0] = 0.f; pp[h][d + 1] = 0.f; pp[h][d + 2] = 0.f; pp[h][d + 3] = 0.f;
        }
    }
    __syncthreads();

    const int sh = tid >> 4;   // score row h
    const int sk = tid & 15;   // score col k'
    float cs = 0.f, ps = 0.f;
#pragma unroll 8
    for (int dd = 0; dd < 64; ++dd) {
        cs += qu[sh][dd] * kk[sk][dd];
        ps += qv[sh][dd] * pp[sk][dd];
    }
    float score = (cs + ps) * 0.03125f;   // /sqrt(1024)
    score = (masks[m] != 0) ? score : 1e-9f;

    // softmax over sk within contiguous 16-lane groups
    float mx = score;
#pragma unroll
    for (int o = 8; o; o >>= 1) mx = fmaxf(mx, __shfl_xor(mx, o, 64));
    float ex = __expf(score - mx);
    float sum = ex;
#pragma unroll
    for (int o = 8; o; o >>= 1) sum += __shfl_xor(sum, o, 64);
    at[sh][sk] = ex / sum;
    __syncthreads();

    // ctx[h][d] = sum_k at[h][k]*v[k][d]; write in output-GEMM layout:
    // row = b2*2048 + h*128 + t2/16, col = (t2%16)*64 + d
#pragma unroll
    for (int j = 0; j < 4; ++j) {
        const int idx = tid + j * 256;
        const int hh = idx >> 6;
        const int dd2 = idx & 63;
        float s = 0.f;
#pragma unroll
        for (int k2 = 0; k2 < 16; ++k2)
            s += at[hh][k2] * vv[k2][dd2];
        const size_t orow = (size_t)b2 * 2048 + hh * 128 + (t2 >> 4);
        ctx[orow * 1024 + (t2 & 15) * 64 + dd2] = f2bf(s);
    }
}

extern "C" void kernel_launch(void* const* d_in, const int* in_sizes, int n_in,
                              void* d_out, int out_size, void* d_ws, size_t ws_size,
                              hipStream_t stream)
{
    (void)in_sizes; (void)n_in; (void)out_size; (void)ws_size;
    const float* inputs = (const float*)d_in[0];
    const float* pos    = (const float*)d_in[1];
    const int*   masks  = (const int*)d_in[2];
    const float* Wq = (const float*)d_in[3];
    const float* bq = (const float*)d_in[4];
    const float* Wk = (const float*)d_in[5];
    const float* bk = (const float*)d_in[6];
    const float* Wv = (const float*)d_in[7];
    const float* bv = (const float*)d_in[8];
    const float* Wp = (const float*)d_in[9];
    const float* Wo = (const float*)d_in[10];
    const float* bo = (const float*)d_in[11];
    const float* ub = (const float*)d_in[12];
    const float* vb = (const float*)d_in[13];

    // ws layout (~170MB, same footprint as round 1):
    //   [0,10MB)      WqT|WkT|WvT|WpT|WoT  (bf16 [N][K], contiguous -> fused QKV B)
    //   [10MB,+64KB)  biascat (f32[3072])
    //   S1 (32MB): pos_bf16 -> inputs_bf16 -> ctx   (sequential reuse)
    //   S2 (32MB): pbuf  (pos @ Wp, bf16)
    //   S3 (96MB): qkv   ([16384][3072] bf16)
    char* ws = (char*)d_ws;
    const size_t WT_SZ = (size_t)1024 * 1024 * 2;
    ushort* WqT = (ushort*)(ws);
    ushort* WkT = (ushort*)(ws + 1 * WT_SZ);
    ushort* WvT = (ushort*)(ws + 2 * WT_SZ);
    ushort* WpT = (ushort*)(ws + 3 * WT_SZ);
    ushort* WoT = (ushort*)(ws + 4 * WT_SZ);
    float*  biascat = (float*)(ws + 5 * WT_SZ);
    char* bufs = ws + 5 * WT_SZ + 65536;
    const size_t S_SZ = (size_t)16384 * 1024 * 2;       // 32MB
    ushort* S1 = (ushort*)(bufs);
    ushort* S2 = (ushort*)(bufs + S_SZ);
    ushort* S3 = (ushort*)(bufs + 2 * S_SZ);            // 96MB

    dim3 blk(256);
    dim3 tgrid(32, 32);

    // weights + biases
    transpose_convert_k<<<tgrid, blk, 0, stream>>>(Wq, WqT, 1024, 1024);
    transpose_convert_k<<<tgrid, blk, 0, stream>>>(Wk, WkT, 1024, 1024);
    transpose_convert_k<<<tgrid, blk, 0, stream>>>(Wv, WvT, 1024, 1024);
    transpose_convert_k<<<tgrid, blk, 0, stream>>>(Wp, WpT, 1024, 1024);
    transpose_convert_k<<<tgrid, blk, 0, stream>>>(Wo, WoT, 1024, 1024);
    bias_concat_k<<<dim3(12), blk, 0, stream>>>(bq, bk, bv, biascat);

    // pos -> bf16 (S1); P-GEMM -> S2
    conv_bf16_k<<<dim3(8192), blk, 0, stream>>>(pos, S1);
    gemm2_k<0, 1><<<dim3(8, 128), blk, 0, stream>>>(S1, WpT, nullptr, S2, 1024, 1024);

    // inputs -> bf16 (S1, overwrites pos_bf16); fused QKV GEMM -> S3
    conv_bf16_k<<<dim3(8192), blk, 0, stream>>>(inputs, S1);
    gemm2_k<1, 1><<<dim3(24, 128), blk, 0, stream>>>(S1, WqT, biascat, S3, 3072, 1024);

    // attention -> ctx (S1, overwrites inputs_bf16)
    attn_k<<<dim3(16384), blk, 0, stream>>>(S3, S2, ub, vb, masks, S1);

    // out = ctx @ Wo + bo  (f32)
    gemm2_k<1, 0><<<dim3(8, 128), blk, 0, stream>>>(S1, WoT, bo, (float*)d_out, 1024, 1024);
}

// Round 3
// 357.318 us; speedup vs baseline: 1.5616x; 1.1403x over previous
//
#include <hip/hip_runtime.h>

// RelativeMultiHeadAttention (B=8, T=2048, D_MODEL=1024, H=16, D_HEAD=64)
// Round 3: 256x256 8-phase GEMM (T2 swizzle + T3/T4 counted vmcnt + T5 setprio),
// fused QKV GEMM (N=3072), f32->bf16 pre-convert of activations.
//
// rel_shift: shifted[m] = pos_score[f=m+8 over flat (b*(T+1)+t)]:
//   b_s = f/2049, t_s = f%2049; zero block if t_s==0 else source (b_s, t_s-1).

typedef __attribute__((ext_vector_type(8))) short short8;
typedef __attribute__((ext_vector_type(4))) float f32x4;

__device__ __forceinline__ ushort f2bf(float f) {
    unsigned u = __float_as_uint(f);
    u += 0x7FFFu + ((u >> 16) & 1u);   // round-to-nearest-even
    return (ushort)(u >> 16);
}
__device__ __forceinline__ float bf2f(ushort u) {
    return __uint_as_float(((unsigned)u) << 16);
}

typedef const unsigned int __attribute__((address_space(1)))* gas_t;
typedef unsigned int __attribute__((address_space(3)))* las_t;
__device__ __forceinline__ void gl_lds16(const ushort* g, ushort* l) {
    // direct global->LDS, 16B per lane; LDS dest = wave-uniform base + lane*16
    __builtin_amdgcn_global_load_lds((gas_t)g, (las_t)l, 16, 0, 0);
}

// ---------------- f32 -> bf16 convert (8 elems/thread) ----------------
__global__ __launch_bounds__(256)
void conv_bf16_k(const float* __restrict__ in, ushort* __restrict__ out)
{
    const size_t i = ((size_t)blockIdx.x * 256 + threadIdx.x) * 8;
    float4 a = *(const float4*)(in + i);
    float4 b = *(const float4*)(in + i + 4);
    short8 o = {(short)f2bf(a.x), (short)f2bf(a.y), (short)f2bf(a.z), (short)f2bf(a.w),
                (short)f2bf(b.x), (short)f2bf(b.y), (short)f2bf(b.z), (short)f2bf(b.w)};
    *(short8*)(out + i) = o;
}

// ---------------- Wt[n][k] = bf16(W[k][n]) ----------------
__global__ __launch_bounds__(256)
void transpose_convert_k(const float* __restrict__ W, ushort* __restrict__ Wt, int K, int N)
{
    __shared__ float tile[32][33];
    const int tx = threadIdx.x & 31;
    const int ty = threadIdx.x >> 5;   // 0..7
    const int n0 = blockIdx.x * 32;
    const int k0 = blockIdx.y * 32;
#pragma unroll
    for (int i = 0; i < 4; ++i)
        tile[ty + i * 8][tx] = W[(size_t)(k0 + ty + i * 8) * N + n0 + tx];
    __syncthreads();
#pragma unroll
    for (int i = 0; i < 4; ++i)
        Wt[(size_t)(n0 + ty + i * 8) * K + k0 + tx] = f2bf(tile[tx][ty + i * 8]);
}

// ---------------- bias concat [bq;bk;bv] ----------------
__global__ __launch_bounds__(256)
void bias_concat_k(const float* __restrict__ b0, const float* __restrict__ b1,
                   const float* __restrict__ b2, float* __restrict__ out)
{
    const int i = blockIdx.x * 256 + threadIdx.x;   // 0..3071
    const int s = i >> 10;
    const int j = i & 1023;
    out[i] = (s == 0) ? b0[j] : (s == 1) ? b1[j] : b2[j];
}

// ======== 256x256 8-phase GEMM: C[M][N] = A[M][K] @ Bt[N][K]^T (+bias) ========
// 512 thr = 8 waves (2x4); per-wave C: 128x64 (8x4 frags of 16x16).
// LDS per operand: [2 dbuf][2 khalf][256 rows][32 cols] bf16 (64KB), total 128KB.
// Swizzle: colbyte ^= ((row>>1)&3)<<4 (both staging-source and ds_read side).
// Phases p=0..3 of K-tile t: (s=p>>1 khalf, mh=p&1 m-half); staging issue:
//   p0: t+1.A.kh1  p1: t+1.B.kh1 [vmcnt 8]  p2: t+2.A.kh0  p3: t+2.B.kh0 [vmcnt 8]
// Region safety: khX last read in its 2 phases, overwrite issued >=1 barrier later.

#define VMC(n) asm volatile("s_waitcnt vmcnt(" #n ")" ::: "memory")

#define STAGE_A(tt, ss) do { \
    ushort* hh = AsF + ((((tt)&1)*2 + (ss)) * 8192) + lchunk; \
    const ushort* gg = Ag + (size_t)(tt) * 64 + (ss) * 32; \
    gl_lds16(gg, hh); \
    gl_lds16(gg + row128, hh + 4096); \
} while (0)

#define STAGE_B(tt, ss) do { \
    ushort* hh = BsF + ((((tt)&1)*2 + (ss)) * 8192) + lchunk; \
    const ushort* gg = Bg + (size_t)(tt) * 64 + (ss) * 32; \
    gl_lds16(gg, hh); \
    gl_lds16(gg + row128, hh + 4096); \
} while (0)

#define PHASE(dd, ss, mh, STAGE_STMT, VM_STMT) do { \
    const ushort* ap = AsF + ((dd)*2 + (ss)) * 8192 + (wr*128 + (mh)*64 + lr) * 32 + fb; \
    const ushort* bp = BsF + ((dd)*2 + (ss)) * 8192 + (wc*64 + lr) * 32 + fb; \
    short8 af[4], bfr[4]; \
    _Pragma("unroll") \
    for (int i_ = 0; i_ < 4; ++i_) af[i_] = *(const short8*)(ap + i_ * 512); \
    _Pragma("unroll") \
    for (int i_ = 0; i_ < 4; ++i_) bfr[i_] = *(const short8*)(bp + i_ * 512); \
    STAGE_STMT; \
    __builtin_amdgcn_s_barrier(); \
    __builtin_amdgcn_sched_barrier(0); \
    __builtin_amdgcn_s_setprio(1); \
    _Pragma("unroll") \
    for (int i_ = 0; i_ < 4; ++i_) \
        _Pragma("unroll") \
        for (int n_ = 0; n_ < 4; ++n_) \
            acc[(mh)*4 + i_][n_] = __builtin_amdgcn_mfma_f32_16x16x32_bf16(af[i_], bfr[n_], acc[(mh)*4 + i_][n_], 0, 0, 0); \
    __builtin_amdgcn_s_setprio(0); \
    __builtin_amdgcn_sched_barrier(0); \
    VM_STMT; \
    __builtin_amdgcn_s_barrier(); \
    __builtin_amdgcn_sched_barrier(0); \
} while (0)

template<int HAS_BIAS, int OUT_BF16>
__global__ __launch_bounds__(512, 2)
void gemm3_k(const ushort* __restrict__ A, const ushort* __restrict__ Bt,
             const float* __restrict__ bias, void* __restrict__ Cv,
             int N, int K)
{
    __shared__ ushort AsF[32768];   // 64KB: [2 dbuf][2 kh][256][32]
    __shared__ ushort BsF[32768];   // 64KB
    const int tid = threadIdx.x;
    const int l = tid & 63;
    const int w = tid >> 6;
    const int wr = w >> 2;             // 0..1
    const int wc = w & 3;              // 0..3
    const int bm = blockIdx.y * 256;
    const int bn = blockIdx.x * 256;
    const int NT = K >> 6;             // K-tiles of 64

    // staging: per half-tile 2 x gl_lds16/thread; chunk c=j*8+w covers rows c*16..+15
    // lane: row l>>2 (chunk-local), physical colbyte (l&3)*16; pre-swizzled global col:
    const int srow = w * 16 + (l >> 2);
    const int scol = ((l & 3) ^ ((l >> 3) & 3)) * 8;
    const ushort* Ag = A  + (size_t)(bm + srow) * K + scol;
    const ushort* Bg = Bt + (size_t)(bn + srow) * K + scol;
    const size_t row128 = (size_t)128 * K;
    const int lchunk = w * 512;        // ushort offset of wave's j=0 chunk

    // frag ds_read: row ...+lr, logical k-off (l>>4)*8; swizzled (lane-constant):
    const int lr = l & 15;
    const int fb = (((l >> 4) ^ ((l >> 1) & 3)) * 8);

    f32x4 acc[8][4];
#pragma unroll
    for (int i = 0; i < 8; ++i)
#pragma unroll
        for (int n = 0; n < 4; ++n)
            acc[i][n] = (f32x4){0.f, 0.f, 0.f, 0.f};

    // prologue: 6 half-tiles; vmcnt(8) lands t0.kh0 (A+B)
    STAGE_A(0, 0); STAGE_B(0, 0);
    STAGE_A(0, 1); STAGE_B(0, 1);
    STAGE_A(1, 0); STAGE_B(1, 0);
    VMC(8);
    __builtin_amdgcn_s_barrier();
    __builtin_amdgcn_sched_barrier(0);

    for (int t = 0; t < NT; ++t) {
        const int d = t & 1;
        PHASE(d, 0, 0, { if (t + 1 < NT) STAGE_A(t + 1, 1); }, {});
        PHASE(d, 0, 1, { if (t + 1 < NT) STAGE_B(t + 1, 1); },
              { if (t == NT - 1) VMC(0); else VMC(8); });
        PHASE(d, 1, 0, { if (t + 2 < NT) STAGE_A(t + 2, 0); }, {});
        PHASE(d, 1, 1, { if (t + 2 < NT) STAGE_B(t + 2, 0); },
              { if (t == NT - 2) VMC(4); else if (t == NT - 1) VMC(0); else VMC(8); });
    }

    // epilogue: C/D layout col=lane&15, row=(lane>>4)*4+reg
    const int cr = (l >> 4) * 4;
    const int cc = l & 15;
    float bv[4];
#pragma unroll
    for (int n = 0; n < 4; ++n)
        bv[n] = HAS_BIAS ? bias[bn + wc * 64 + n * 16 + cc] : 0.f;
#pragma unroll
    for (int m = 0; m < 8; ++m) {
#pragma unroll
        for (int n = 0; n < 4; ++n) {
            const int col = bn + wc * 64 + n * 16 + cc;
#pragma unroll
            for (int r = 0; r < 4; ++r) {
                const int row = bm + wr * 128 + m * 16 + cr + r;
                float v = acc[m][n][r] + bv[n];
                if (OUT_BF16) ((ushort*)Cv)[(size_t)row * N + col] = f2bf(v);
                else          ((float*)Cv)[(size_t)row * N + col] = v;
            }
        }
    }
}

// ---------------- per-(b,t) attention ----------------
// qkv: [16384][3072] (q|k|v per timestep), pbuf: [16384][1024]
__global__ __launch_bounds__(256)
void attn_k(const ushort* __restrict__ qkv, const ushort* __restrict__ pbuf,
            const float* __restrict__ ubias, const float* __restrict__ vbias,
            const int* __restrict__ masks, ushort* __restrict__ ctx)
{
    __shared__ float qu[16][65];   // q(m)+u_bias
    __shared__ float kk[16][65];
    __shared__ float vv[16][65];
    __shared__ float qv[16][65];   // q(mp)+v_bias (rel-shift source)
    __shared__ float pp[16][65];
    __shared__ float at[16][16];

    const int m  = blockIdx.x;         // b2*T + t2
    const int b2 = m >> 11;
    const int t2 = m & 2047;
    const int f  = m + 8;              // rel-shift: flat block index + B
    const int bs = f / 2049;
    const int ts = f - bs * 2049;
    const bool haspos = (ts != 0);     // ts==0 -> zero pad row
    const int mp = bs * 2048 + ts - 1;

    const int tid = threadIdx.x;
    const int e = tid * 4;
    const int h = e >> 6;
    const int d = e & 63;

    {
        const ushort* base = qkv + (size_t)m * 3072;
        ushort4 a = *(const ushort4*)(base + e);
        ushort4 b = *(const ushort4*)(base + 1024 + e);
        ushort4 c = *(const ushort4*)(base + 2048 + e);
        float4 uu = *(const float4*)(ubias + e);
        qu[h][d + 0] = bf2f(a.x) + uu.x;
        qu[h][d + 1] = bf2f(a.y) + uu.y;
        qu[h][d + 2] = bf2f(a.z) + uu.z;
        qu[h][d + 3] = bf2f(a.w) + uu.w;
        kk[h][d + 0] = bf2f(b.x);
        kk[h][d + 1] = bf2f(b.y);
        kk[h][d + 2] = bf2f(b.z);
        kk[h][d + 3] = bf2f(b.w);
        vv[h][d + 0] = bf2f(c.x);
        vv[h][d + 1] = bf2f(c.y);
        vv[h][d + 2] = bf2f(c.z);
        vv[h][d + 3] = bf2f(c.w);
        if (haspos) {
            ushort4 qq = *(const ushort4*)(qkv + (size_t)mp * 3072 + e);
            ushort4 pq = *(const ushort4*)(pbuf + (size_t)mp * 1024 + e);
            float4 vv4 = *(const float4*)(vbias + e);
            qv[h][d + 0] = bf2f(qq.x) + vv4.x;
            qv[h][d + 1] = bf2f(qq.y) + vv4.y;
            qv[h][d + 2] = bf2f(qq.z) + vv4.z;
            qv[h][d + 3] = bf2f(qq.w) + vv4.w;
            pp[h][d + 0] = bf2f(pq.x);
            pp[h][d + 1] = bf2f(pq.y);
            pp[h][d + 2] = bf2f(pq.z);
            pp[h][d + 3] = bf2f(pq.w);
        } else {
            qv[h][d + 0] = 0.f; qv[h][d + 1] = 0.f; qv[h][d + 2] = 0.f; qv[h][d + 3] = 0.f;
            pp[h][d + 0] = 0.f; pp[h][d + 1] = 0.f; pp[h][d + 2] = 0.f; pp[h][d + 3] = 0.f;
        }
    }
    __syncthreads();

    const int sh = tid >> 4;   // score row h
    const int sk = tid & 15;   // score col k'
    float cs = 0.f, ps = 0.f;
#pragma unroll 8
    for (int dd = 0; dd < 64; ++dd) {
        cs += qu[sh][dd] * kk[sk][dd];
        ps += qv[sh][dd] * pp[sk][dd];
    }
    float score = (cs + ps) * 0.03125f;   // /sqrt(1024)
    score = (masks[m] != 0) ? score : 1e-9f;

    // softmax over sk within contiguous 16-lane groups
    float mx = score;
#pragma unroll
    for (int o = 8; o; o >>= 1) mx = fmaxf(mx, __shfl_xor(mx, o, 64));
    float ex = __expf(score - mx);
    float sum = ex;
#pragma unroll
    for (int o = 8; o; o >>= 1) sum += __shfl_xor(sum, o, 64);
    at[sh][sk] = ex / sum;
    __syncthreads();

    // ctx[h][d] = sum_k at[h][k]*v[k][d]; write in output-GEMM layout:
    // row = b2*2048 + h*128 + t2/16, col = (t2%16)*64 + d
#pragma unroll
    for (int j = 0; j < 4; ++j) {
        const int idx = tid + j * 256;
        const int hh = idx >> 6;
        const int dd2 = idx & 63;
        float s = 0.f;
#pragma unroll
        for (int k2 = 0; k2 < 16; ++k2)
            s += at[hh][k2] * vv[k2][dd2];
        const size_t orow = (size_t)b2 * 2048 + hh * 128 + (t2 >> 4);
        ctx[orow * 1024 + (t2 & 15) * 64 + dd2] = f2bf(s);
    }
}

extern "C" void kernel_launch(void* const* d_in, const int* in_sizes, int n_in,
                              void* d_out, int out_size, void* d_ws, size_t ws_size,
                              hipStream_t stream)
{
    (void)in_sizes; (void)n_in; (void)out_size; (void)ws_size;
    const float* inputs = (const float*)d_in[0];
    const float* pos    = (const float*)d_in[1];
    const int*   masks  = (const int*)d_in[2];
    const float* Wq = (const float*)d_in[3];
    const float* bq = (const float*)d_in[4];
    const float* Wk = (const float*)d_in[5];
    const float* bk = (const float*)d_in[6];
    const float* Wv = (const float*)d_in[7];
    const float* bv = (const float*)d_in[8];
    const float* Wp = (const float*)d_in[9];
    const float* Wo = (const float*)d_in[10];
    const float* bo = (const float*)d_in[11];
    const float* ub = (const float*)d_in[12];
    const float* vb = (const float*)d_in[13];

    // ws layout:
    //   [0,10MB)      WqT|WkT|WvT|WpT|WoT  (bf16 [N][K], contiguous -> fused QKV B)
    //   [10MB,+64KB)  biascat (f32[3072])
    //   S1 (32MB): pos_bf16 -> inputs_bf16 -> ctx   (sequential reuse)
    //   S2 (32MB): pbuf  (pos @ Wp, bf16)
    //   S3 (96MB): qkv   ([16384][3072] bf16)
    char* ws = (char*)d_ws;
    const size_t WT_SZ = (size_t)1024 * 1024 * 2;
    ushort* WqT = (ushort*)(ws);
    ushort* WkT = (ushort*)(ws + 1 * WT_SZ);
    ushort* WvT = (ushort*)(ws + 2 * WT_SZ);
    ushort* WpT = (ushort*)(ws + 3 * WT_SZ);
    ushort* WoT = (ushort*)(ws + 4 * WT_SZ);
    float*  biascat = (float*)(ws + 5 * WT_SZ);
    char* bufs = ws + 5 * WT_SZ + 65536;
    const size_t S_SZ = (size_t)16384 * 1024 * 2;       // 32MB
    ushort* S1 = (ushort*)(bufs);
    ushort* S2 = (ushort*)(bufs + S_SZ);
    ushort* S3 = (ushort*)(bufs + 2 * S_SZ);            // 96MB

    dim3 blk(256);
    dim3 tgrid(32, 32);

    // weights + biases
    transpose_convert_k<<<tgrid, blk, 0, stream>>>(Wq, WqT, 1024, 1024);
    transpose_convert_k<<<tgrid, blk, 0, stream>>>(Wk, WkT, 1024, 1024);
    transpose_convert_k<<<tgrid, blk, 0, stream>>>(Wv, WvT, 1024, 1024);
    transpose_convert_k<<<tgrid, blk, 0, stream>>>(Wp, WpT, 1024, 1024);
    transpose_convert_k<<<tgrid, blk, 0, stream>>>(Wo, WoT, 1024, 1024);
    bias_concat_k<<<dim3(12), blk, 0, stream>>>(bq, bk, bv, biascat);

    // pos -> bf16 (S1); P-GEMM -> S2
    conv_bf16_k<<<dim3(8192), blk, 0, stream>>>(pos, S1);
    gemm3_k<0, 1><<<dim3(4, 64), dim3(512), 0, stream>>>(S1, WpT, nullptr, S2, 1024, 1024);

    // inputs -> bf16 (S1); fused QKV GEMM -> S3
    conv_bf16_k<<<dim3(8192), blk, 0, stream>>>(inputs, S1);
    gemm3_k<1, 1><<<dim3(12, 64), dim3(512), 0, stream>>>(S1, WqT, biascat, S3, 3072, 1024);

    // attention -> ctx (S1, overwrites inputs_bf16)
    attn_k<<<dim3(16384), blk, 0, stream>>>(S3, S2, ub, vb, masks, S1);

    // out = ctx @ Wo + bo  (f32)
    gemm3_k<1, 0><<<dim3(4, 64), dim3(512), 0, stream>>>(S1, WoT, bo, (float*)d_out, 1024, 1024);
}

// Round 4
// 331.945 us; speedup vs baseline: 1.6809x; 1.0764x over previous
//
#include <hip/hip_runtime.h>

// RelativeMultiHeadAttention (B=8, T=2048, D_MODEL=1024, H=16, D_HEAD=64)
// Round 4: 256x256 GEMM, 2 phases/K-tile (32-MFMA clusters, kh-split),
// XCD/L2-aware bijective block remap, counted vmcnt, T2 swizzle, T5 setprio.
//
// rel_shift: shifted[m] = pos_score[f=m+8 over flat (b*(T+1)+t)]:
//   b_s = f/2049, t_s = f%2049; zero block if t_s==0 else source (b_s, t_s-1).

typedef __attribute__((ext_vector_type(8))) short short8;
typedef __attribute__((ext_vector_type(4))) float f32x4;

__device__ __forceinline__ ushort f2bf(float f) {
    unsigned u = __float_as_uint(f);
    u += 0x7FFFu + ((u >> 16) & 1u);   // round-to-nearest-even
    return (ushort)(u >> 16);
}
__device__ __forceinline__ float bf2f(ushort u) {
    return __uint_as_float(((unsigned)u) << 16);
}

typedef const unsigned int __attribute__((address_space(1)))* gas_t;
typedef unsigned int __attribute__((address_space(3)))* las_t;
__device__ __forceinline__ void gl_lds16(const ushort* g, ushort* l) {
    // direct global->LDS, 16B per lane; LDS dest = wave-uniform base + lane*16
    __builtin_amdgcn_global_load_lds((gas_t)g, (las_t)l, 16, 0, 0);
}

// ---------------- f32 -> bf16 convert (8 elems/thread) ----------------
__global__ __launch_bounds__(256)
void conv_bf16_k(const float* __restrict__ in, ushort* __restrict__ out)
{
    const size_t i = ((size_t)blockIdx.x * 256 + threadIdx.x) * 8;
    float4 a = *(const float4*)(in + i);
    float4 b = *(const float4*)(in + i + 4);
    short8 o = {(short)f2bf(a.x), (short)f2bf(a.y), (short)f2bf(a.z), (short)f2bf(a.w),
                (short)f2bf(b.x), (short)f2bf(b.y), (short)f2bf(b.z), (short)f2bf(b.w)};
    *(short8*)(out + i) = o;
}

// ---------------- Wt[n][k] = bf16(W[k][n]) ----------------
__global__ __launch_bounds__(256)
void transpose_convert_k(const float* __restrict__ W, ushort* __restrict__ Wt, int K, int N)
{
    __shared__ float tile[32][33];
    const int tx = threadIdx.x & 31;
    const int ty = threadIdx.x >> 5;   // 0..7
    const int n0 = blockIdx.x * 32;
    const int k0 = blockIdx.y * 32;
#pragma unroll
    for (int i = 0; i < 4; ++i)
        tile[ty + i * 8][tx] = W[(size_t)(k0 + ty + i * 8) * N + n0 + tx];
    __syncthreads();
#pragma unroll
    for (int i = 0; i < 4; ++i)
        Wt[(size_t)(n0 + ty + i * 8) * K + k0 + tx] = f2bf(tile[tx][ty + i * 8]);
}

// ---------------- bias concat [bq;bk;bv] ----------------
__global__ __launch_bounds__(256)
void bias_concat_k(const float* __restrict__ b0, const float* __restrict__ b1,
                   const float* __restrict__ b2, float* __restrict__ out)
{
    const int i = blockIdx.x * 256 + threadIdx.x;   // 0..3071
    const int s = i >> 10;
    const int j = i & 1023;
    out[i] = (s == 0) ? b0[j] : (s == 1) ? b1[j] : b2[j];
}

// ======== 256x256 GEMM, 2 phases/K-tile: C[M][N] = A[M][K] @ Bt[N][K]^T ========
// 512 thr = 8 waves (2x4); per-wave C: 128x64 (8x4 frags of 16x16).
// LDS per operand: [2 dbuf][2 khalf][256 rows][32 cols] bf16 (64KB), total 128KB.
// Swizzle: colbyte ^= ((row>>1)&3)<<4 (staging-source AND ds_read side).
// Phase (t, s=kh): ds_read t.khs (A 8 + B 4 x b128), stage issue, barrier,
//   32 MFMA (setprio), counted vmcnt, barrier.
//   P0 stages t+1.kh1 (A+B, 4 loads); P1 stages t+2.kh0 (A+B, 4 loads).
// Steady 12 loads in flight; VMC(8) lands exactly the 4 needed next phase.
// Tail: P1@NT-2 -> VMC(4); both phases @NT-1 -> VMC(0).
// Region safety: khX last read in its phase completes before that phase's
// MFMA-barrier; overwrite for t+2/t+1 issued >=1 barrier later.

#define VMC(n) asm volatile("s_waitcnt vmcnt(" #n ")" ::: "memory")

#define STAGE_A(tt, ss) do { \
    ushort* hh = AsF + ((((tt)&1)*2 + (ss)) * 8192) + lchunk; \
    const ushort* gg = Ag + (size_t)(tt) * 64 + (ss) * 32; \
    gl_lds16(gg, hh); \
    gl_lds16(gg + row128, hh + 4096); \
} while (0)

#define STAGE_B(tt, ss) do { \
    ushort* hh = BsF + ((((tt)&1)*2 + (ss)) * 8192) + lchunk; \
    const ushort* gg = Bg + (size_t)(tt) * 64 + (ss) * 32; \
    gl_lds16(gg, hh); \
    gl_lds16(gg + row128, hh + 4096); \
} while (0)

#define PHASE2(dd, ss, STAGE_STMT, VM_STMT) do { \
    const ushort* ap = AsF + ((dd)*2 + (ss)) * 8192 + (wr*128 + lr) * 32 + fb; \
    const ushort* bp = BsF + ((dd)*2 + (ss)) * 8192 + (wc*64 + lr) * 32 + fb; \
    short8 af[8], bfr[4]; \
    _Pragma("unroll") \
    for (int i_ = 0; i_ < 8; ++i_) af[i_] = *(const short8*)(ap + i_ * 512); \
    _Pragma("unroll") \
    for (int i_ = 0; i_ < 4; ++i_) bfr[i_] = *(const short8*)(bp + i_ * 512); \
    STAGE_STMT; \
    __builtin_amdgcn_s_barrier(); \
    __builtin_amdgcn_sched_barrier(0); \
    __builtin_amdgcn_s_setprio(1); \
    _Pragma("unroll") \
    for (int i_ = 0; i_ < 8; ++i_) \
        _Pragma("unroll") \
        for (int n_ = 0; n_ < 4; ++n_) \
            acc[i_][n_] = __builtin_amdgcn_mfma_f32_16x16x32_bf16(af[i_], bfr[n_], acc[i_][n_], 0, 0, 0); \
    __builtin_amdgcn_s_setprio(0); \
    __builtin_amdgcn_sched_barrier(0); \
    VM_STMT; \
    __builtin_amdgcn_s_barrier(); \
    __builtin_amdgcn_sched_barrier(0); \
} while (0)

template<int HAS_BIAS, int OUT_BF16>
__global__ __launch_bounds__(512, 2)
void gemm4_k(const ushort* __restrict__ A, const ushort* __restrict__ Bt,
             const float* __restrict__ bias, void* __restrict__ Cv,
             int N, int K)
{
    __shared__ ushort AsF[32768];   // 64KB: [2 dbuf][2 kh][256][32]
    __shared__ ushort BsF[32768];   // 64KB
    const int tid = threadIdx.x;
    const int l = tid & 63;
    const int w = tid >> 6;
    const int wr = w >> 2;             // 0..1
    const int wc = w & 3;              // 0..3

    // XCD/L2-aware bijective remap: each XCD owns a y-band (gy/8 rows of
    // 256), traversed in 4x4 block sub-tiles. Requires gx%4==0, gy%8==0.
    const int gx = gridDim.x;
    const int lin = blockIdx.y * gx + blockIdx.x;
    const int xcd = lin & 7;
    const int idx = lin >> 3;          // 0 .. gx*(gy/8)-1
    const int hb = gridDim.y >> 3;     // y-band height (blocks)
    const int sxc = gx >> 2;           // 4-wide x sub-tiles
    const int g4 = idx >> 4;
    const int li = idx & 15;
    const int bx = (g4 % sxc) * 4 + (li & 3);
    const int by = xcd * hb + (g4 / sxc) * 4 + (li >> 2);
    const int bm = by * 256;
    const int bn = bx * 256;
    const int NT = K >> 6;             // K-tiles of 64

    // staging: chunk c=j*8+w covers rows c*16..+15; lane: row l>>2,
    // physical colbyte (l&3)*16; pre-swizzled global col:
    const int srow = w * 16 + (l >> 2);
    const int scol = ((l & 3) ^ ((l >> 3) & 3)) * 8;
    const ushort* Ag = A  + (size_t)(bm + srow) * K + scol;
    const ushort* Bg = Bt + (size_t)(bn + srow) * K + scol;
    const size_t row128 = (size_t)128 * K;
    const int lchunk = w * 512;        // ushort offset of wave's j=0 chunk

    // frag ds_read: row ...+lr, logical k-off (l>>4)*8; swizzled (lane-constant):
    const int lr = l & 15;
    const int fb = (((l >> 4) ^ ((l >> 1) & 3)) * 8);

    f32x4 acc[8][4];
#pragma unroll
    for (int i = 0; i < 8; ++i)
#pragma unroll
        for (int n = 0; n < 4; ++n)
            acc[i][n] = (f32x4){0.f, 0.f, 0.f, 0.f};

    // prologue: 6 half-tiles (12 loads); vmcnt(8) lands t0.kh0 (A+B)
    STAGE_A(0, 0); STAGE_B(0, 0);
    STAGE_A(0, 1); STAGE_B(0, 1);
    STAGE_A(1, 0); STAGE_B(1, 0);
    VMC(8);
    __builtin_amdgcn_s_barrier();
    __builtin_amdgcn_sched_barrier(0);

    for (int t = 0; t < NT; ++t) {
        const int d = t & 1;
        PHASE2(d, 0, { if (t + 1 < NT) { STAGE_A(t + 1, 1); STAGE_B(t + 1, 1); } },
               { if (t == NT - 1) VMC(0); else VMC(8); });
        PHASE2(d, 1, { if (t + 2 < NT) { STAGE_A(t + 2, 0); STAGE_B(t + 2, 0); } },
               { if (t == NT - 2) VMC(4); else if (t == NT - 1) VMC(0); else VMC(8); });
    }

    // epilogue: C/D layout col=lane&15, row=(lane>>4)*4+reg
    const int cr = (l >> 4) * 4;
    const int cc = l & 15;
    float bv[4];
#pragma unroll
    for (int n = 0; n < 4; ++n)
        bv[n] = HAS_BIAS ? bias[bn + wc * 64 + n * 16 + cc] : 0.f;
#pragma unroll
    for (int m = 0; m < 8; ++m) {
#pragma unroll
        for (int n = 0; n < 4; ++n) {
            const int col = bn + wc * 64 + n * 16 + cc;
#pragma unroll
            for (int r = 0; r < 4; ++r) {
                const int row = bm + wr * 128 + m * 16 + cr + r;
                float v = acc[m][n][r] + bv[n];
                if (OUT_BF16) ((ushort*)Cv)[(size_t)row * N + col] = f2bf(v);
                else          ((float*)Cv)[(size_t)row * N + col] = v;
            }
        }
    }
}

// ---------------- per-(b,t) attention ----------------
// qkv: [16384][3072] (q|k|v per timestep), pbuf: [16384][1024]
__global__ __launch_bounds__(256)
void attn_k(const ushort* __restrict__ qkv, const ushort* __restrict__ pbuf,
            const float* __restrict__ ubias, const float* __restrict__ vbias,
            const int* __restrict__ masks, ushort* __restrict__ ctx)
{
    __shared__ float qu[16][65];   // q(m)+u_bias
    __shared__ float kk[16][65];
    __shared__ float vv[16][65];
    __shared__ float qv[16][65];   // q(mp)+v_bias (rel-shift source)
    __shared__ float pp[16][65];
    __shared__ float at[16][16];

    const int m  = blockIdx.x;         // b2*T + t2
    const int b2 = m >> 11;
    const int t2 = m & 2047;
    const int f  = m + 8;              // rel-shift: flat block index + B
    const int bs = f / 2049;
    const int ts = f - bs * 2049;
    const bool haspos = (ts != 0);     // ts==0 -> zero pad row
    const int mp = bs * 2048 + ts - 1;

    const int tid = threadIdx.x;
    const int e = tid * 4;
    const int h = e >> 6;
    const int d = e & 63;

    {
        const ushort* base = qkv + (size_t)m * 3072;
        ushort4 a = *(const ushort4*)(base + e);
        ushort4 b = *(const ushort4*)(base + 1024 + e);
        ushort4 c = *(const ushort4*)(base + 2048 + e);
        float4 uu = *(const float4*)(ubias + e);
        qu[h][d + 0] = bf2f(a.x) + uu.x;
        qu[h][d + 1] = bf2f(a.y) + uu.y;
        qu[h][d + 2] = bf2f(a.z) + uu.z;
        qu[h][d + 3] = bf2f(a.w) + uu.w;
        kk[h][d + 0] = bf2f(b.x);
        kk[h][d + 1] = bf2f(b.y);
        kk[h][d + 2] = bf2f(b.z);
        kk[h][d + 3] = bf2f(b.w);
        vv[h][d + 0] = bf2f(c.x);
        vv[h][d + 1] = bf2f(c.y);
        vv[h][d + 2] = bf2f(c.z);
        vv[h][d + 3] = bf2f(c.w);
        if (haspos) {
            ushort4 qq = *(const ushort4*)(qkv + (size_t)mp * 3072 + e);
            ushort4 pq = *(const ushort4*)(pbuf + (size_t)mp * 1024 + e);
            float4 vv4 = *(const float4*)(vbias + e);
            qv[h][d + 0] = bf2f(qq.x) + vv4.x;
            qv[h][d + 1] = bf2f(qq.y) + vv4.y;
            qv[h][d + 2] = bf2f(qq.z) + vv4.z;
            qv[h][d + 3] = bf2f(qq.w) + vv4.w;
            pp[h][d + 0] = bf2f(pq.x);
            pp[h][d + 1] = bf2f(pq.y);
            pp[h][d + 2] = bf2f(pq.z);
            pp[h][d + 3] = bf2f(pq.w);
        } else {
            qv[h][d + 0] = 0.f; qv[h][d + 1] = 0.f; qv[h][d + 2] = 0.f; qv[h][d + 3] = 0.f;
            pp[h][d + 0] = 0.f; pp[h][d + 1] = 0.f; pp[h][d + 2] = 0.f; pp[h][d + 3] = 0.f;
        }
    }
    __syncthreads();

    const int sh = tid >> 4;   // score row h
    const int sk = tid & 15;   // score col k'
    float cs = 0.f, ps = 0.f;
#pragma unroll 8
    for (int dd = 0; dd < 64; ++dd) {
        cs += qu[sh][dd] * kk[sk][dd];
        ps += qv[sh][dd] * pp[sk][dd];
    }
    float score = (cs + ps) * 0.03125f;   // /sqrt(1024)
    score = (masks[m] != 0) ? score : 1e-9f;

    // softmax over sk within contiguous 16-lane groups
    float mx = score;
#pragma unroll
    for (int o = 8; o; o >>= 1) mx = fmaxf(mx, __shfl_xor(mx, o, 64));
    float ex = __expf(score - mx);
    float sum = ex;
#pragma unroll
    for (int o = 8; o; o >>= 1) sum += __shfl_xor(sum, o, 64);
    at[sh][sk] = ex / sum;
    __syncthreads();

    // ctx[h][d] = sum_k at[h][k]*v[k][d]; write in output-GEMM layout:
    // row = b2*2048 + h*128 + t2/16, col = (t2%16)*64 + d
#pragma unroll
    for (int j = 0; j < 4; ++j) {
        const int idx = tid + j * 256;
        const int hh = idx >> 6;
        const int dd2 = idx & 63;
        float s = 0.f;
#pragma unroll
        for (int k2 = 0; k2 < 16; ++k2)
            s += at[hh][k2] * vv[k2][dd2];
        const size_t orow = (size_t)b2 * 2048 + hh * 128 + (t2 >> 4);
        ctx[orow * 1024 + (t2 & 15) * 64 + dd2] = f2bf(s);
    }
}

extern "C" void kernel_launch(void* const* d_in, const int* in_sizes, int n_in,
                              void* d_out, int out_size, void* d_ws, size_t ws_size,
                              hipStream_t stream)
{
    (void)in_sizes; (void)n_in; (void)out_size; (void)ws_size;
    const float* inputs = (const float*)d_in[0];
    const float* pos    = (const float*)d_in[1];
    const int*   masks  = (const int*)d_in[2];
    const float* Wq = (const float*)d_in[3];
    const float* bq = (const float*)d_in[4];
    const float* Wk = (const float*)d_in[5];
    const float* bk = (const float*)d_in[6];
    const float* Wv = (const float*)d_in[7];
    const float* bv = (const float*)d_in[8];
    const float* Wp = (const float*)d_in[9];
    const float* Wo = (const float*)d_in[10];
    const float* bo = (const float*)d_in[11];
    const float* ub = (const float*)d_in[12];
    const float* vb = (const float*)d_in[13];

    // ws layout:
    //   [0,10MB)      WqT|WkT|WvT|WpT|WoT  (bf16 [N][K], contiguous -> fused QKV B)
    //   [10MB,+64KB)  biascat (f32[3072])
    //   S1 (32MB): pos_bf16 -> inputs_bf16 -> ctx   (sequential reuse)
    //   S2 (32MB): pbuf  (pos @ Wp, bf16)
    //   S3 (96MB): qkv   ([16384][3072] bf16)
    char* ws = (char*)d_ws;
    const size_t WT_SZ = (size_t)1024 * 1024 * 2;
    ushort* WqT = (ushort*)(ws);
    ushort* WkT = (ushort*)(ws + 1 * WT_SZ);
    ushort* WvT = (ushort*)(ws + 2 * WT_SZ);
    ushort* WpT = (ushort*)(ws + 3 * WT_SZ);
    ushort* WoT = (ushort*)(ws + 4 * WT_SZ);
    float*  biascat = (float*)(ws + 5 * WT_SZ);
    char* bufs = ws + 5 * WT_SZ + 65536;
    const size_t S_SZ = (size_t)16384 * 1024 * 2;       // 32MB
    ushort* S1 = (ushort*)(bufs);
    ushort* S2 = (ushort*)(bufs + S_SZ);
    ushort* S3 = (ushort*)(bufs + 2 * S_SZ);            // 96MB

    dim3 blk(256);
    dim3 tgrid(32, 32);

    // weights + biases
    transpose_convert_k<<<tgrid, blk, 0, stream>>>(Wq, WqT, 1024, 1024);
    transpose_convert_k<<<tgrid, blk, 0, stream>>>(Wk, WkT, 1024, 1024);
    transpose_convert_k<<<tgrid, blk, 0, stream>>>(Wv, WvT, 1024, 1024);
    transpose_convert_k<<<tgrid, blk, 0, stream>>>(Wp, WpT, 1024, 1024);
    transpose_convert_k<<<tgrid, blk, 0, stream>>>(Wo, WoT, 1024, 1024);
    bias_concat_k<<<dim3(12), blk, 0, stream>>>(bq, bk, bv, biascat);

    // pos -> bf16 (S1); P-GEMM -> S2
    conv_bf16_k<<<dim3(8192), blk, 0, stream>>>(pos, S1);
    gemm4_k<0, 1><<<dim3(4, 64), dim3(512), 0, stream>>>(S1, WpT, nullptr, S2, 1024, 1024);

    // inputs -> bf16 (S1); fused QKV GEMM -> S3
    conv_bf16_k<<<dim3(8192), blk, 0, stream>>>(inputs, S1);
    gemm4_k<1, 1><<<dim3(12, 64), dim3(512), 0, stream>>>(S1, WqT, biascat, S3, 3072, 1024);

    // attention -> ctx (S1, overwrites inputs_bf16)
    attn_k<<<dim3(16384), blk, 0, stream>>>(S3, S2, ub, vb, masks, S1);

    // out = ctx @ Wo + bo  (f32)
    gemm4_k<1, 0><<<dim3(4, 64), dim3(512), 0, stream>>>(S1, WoT, bo, (float*)d_out, 1024, 1024);
}

// Round 5
// 328.653 us; speedup vs baseline: 1.6978x; 1.0100x over previous
//
#include <hip/hip_runtime.h>

// RelativeMultiHeadAttention (B=8, T=2048, D_MODEL=1024, H=16, D_HEAD=64)
// Round 5: m201-style fine-interleaved 4-phase/K-tile 256x256 GEMM
// (T2 swizzle + T3/T4 counted vmcnt(4) + T5 setprio + T1 XCD remap),
// B-frag register reuse across m-half phases.
//
// rel_shift: shifted[m] = pos_score[f=m+8 over flat (b*(T+1)+t)]:
//   b_s = f/2049, t_s = f%2049; zero block if t_s==0 else source (b_s, t_s-1).

typedef __attribute__((ext_vector_type(8))) short short8;
typedef __attribute__((ext_vector_type(4))) float f32x4;

__device__ __forceinline__ ushort f2bf(float f) {
    unsigned u = __float_as_uint(f);
    u += 0x7FFFu + ((u >> 16) & 1u);   // round-to-nearest-even
    return (ushort)(u >> 16);
}
__device__ __forceinline__ float bf2f(ushort u) {
    return __uint_as_float(((unsigned)u) << 16);
}

typedef const unsigned int __attribute__((address_space(1)))* gas_t;
typedef unsigned int __attribute__((address_space(3)))* las_t;
__device__ __forceinline__ void gl_lds16(const ushort* g, ushort* l) {
    // direct global->LDS, 16B per lane; LDS dest = wave-uniform base + lane*16
    __builtin_amdgcn_global_load_lds((gas_t)g, (las_t)l, 16, 0, 0);
}

// ---------------- f32 -> bf16 convert (8 elems/thread) ----------------
__global__ __launch_bounds__(256)
void conv_bf16_k(const float* __restrict__ in, ushort* __restrict__ out)
{
    const size_t i = ((size_t)blockIdx.x * 256 + threadIdx.x) * 8;
    float4 a = *(const float4*)(in + i);
    float4 b = *(const float4*)(in + i + 4);
    short8 o = {(short)f2bf(a.x), (short)f2bf(a.y), (short)f2bf(a.z), (short)f2bf(a.w),
                (short)f2bf(b.x), (short)f2bf(b.y), (short)f2bf(b.z), (short)f2bf(b.w)};
    *(short8*)(out + i) = o;
}

// ---------------- Wt[n][k] = bf16(W[k][n]) ----------------
__global__ __launch_bounds__(256)
void transpose_convert_k(const float* __restrict__ W, ushort* __restrict__ Wt, int K, int N)
{
    __shared__ float tile[32][33];
    const int tx = threadIdx.x & 31;
    const int ty = threadIdx.x >> 5;   // 0..7
    const int n0 = blockIdx.x * 32;
    const int k0 = blockIdx.y * 32;
#pragma unroll
    for (int i = 0; i < 4; ++i)
        tile[ty + i * 8][tx] = W[(size_t)(k0 + ty + i * 8) * N + n0 + tx];
    __syncthreads();
#pragma unroll
    for (int i = 0; i < 4; ++i)
        Wt[(size_t)(n0 + ty + i * 8) * K + k0 + tx] = f2bf(tile[tx][ty + i * 8]);
}

// ---------------- bias concat [bq;bk;bv] ----------------
__global__ __launch_bounds__(256)
void bias_concat_k(const float* __restrict__ b0, const float* __restrict__ b1,
                   const float* __restrict__ b2, float* __restrict__ out)
{
    const int i = blockIdx.x * 256 + threadIdx.x;   // 0..3071
    const int s = i >> 10;
    const int j = i & 1023;
    out[i] = (s == 0) ? b0[j] : (s == 1) ? b1[j] : b2[j];
}

// ======== 256x256 GEMM, 4 fine phases/K-tile: C = A[M][K] @ Bt[N][K]^T ========
// 512 thr = 8 waves (2x4); per-wave C: 128x64 (8x4 frags of 16x16).
// LDS per operand: [2 dbuf][2 khalf][256 rows][32 cols] bf16 (64KB), total 128KB.
// Swizzle: colbyte ^= ((row>>1)&3)<<4 (staging-source AND ds_read side).
// Phase (t, kh=ss, mh): ds_read A-subtile (4 x b128) (+B 4 x b128 iff mh==0,
//   regs persist to mh==1), issue 1 half-stage (2 gl_lds16), barrier,
//   lgkmcnt(0), 16 MFMA (setprio), counted vmcnt, barrier.
// Stage issue: (t,0)->A.kh0(t+1) (t,1)->B.kh0(t+1) (t,2)->A.kh1(t+1) (t,3)->B.kh1(t+1)
// FIFO: end-P1 outstanding {A1t,B1t,A0t1,B0t1}=8 -> VMC(4) lands A1t,B1t (P2 needs);
//       end-P3 outstanding {A0,B0,A1,B1}t+1 =8 -> VMC(4) lands A0,B0 (next P0 needs).
// Tail t=NT-1: no issue; end-P1 VMC(0); end-P3 nothing outstanding.
// Region safety: every staged region's overwrite issues >=2 barriers after its
// last ds_read (dbuf alternation + phase ordering).

#define VMC(n) asm volatile("s_waitcnt vmcnt(" #n ")" ::: "memory")

#define STAGE_A(tt, ss) do { \
    ushort* hh = AsF + ((((tt)&1)*2 + (ss)) * 8192) + lchunk; \
    const ushort* gg = Ag + (size_t)(tt) * 64 + (ss) * 32; \
    gl_lds16(gg, hh); \
    gl_lds16(gg + row128, hh + 4096); \
} while (0)

#define STAGE_B(tt, ss) do { \
    ushort* hh = BsF + ((((tt)&1)*2 + (ss)) * 8192) + lchunk; \
    const ushort* gg = Bg + (size_t)(tt) * 64 + (ss) * 32; \
    gl_lds16(gg, hh); \
    gl_lds16(gg + row128, hh + 4096); \
} while (0)

#define PHASE5(dd, ss, mh, READ_B, STAGE_STMT, VM_STMT) do { \
    const ushort* ap = AsF + ((dd)*2 + (ss)) * 8192 + (wr*128 + (mh)*64 + lr) * 32 + fb; \
    short8 af[4]; \
    _Pragma("unroll") \
    for (int i_ = 0; i_ < 4; ++i_) af[i_] = *(const short8*)(ap + i_ * 512); \
    if (READ_B) { \
        const ushort* bp = BsF + ((dd)*2 + (ss)) * 8192 + (wc*64 + lr) * 32 + fb; \
        _Pragma("unroll") \
        for (int n_ = 0; n_ < 4; ++n_) bfr[n_] = *(const short8*)(bp + n_ * 512); \
    } \
    STAGE_STMT; \
    __builtin_amdgcn_s_barrier(); \
    asm volatile("s_waitcnt lgkmcnt(0)" ::: "memory"); \
    __builtin_amdgcn_sched_barrier(0); \
    __builtin_amdgcn_s_setprio(1); \
    _Pragma("unroll") \
    for (int i_ = 0; i_ < 4; ++i_) \
        _Pragma("unroll") \
        for (int n_ = 0; n_ < 4; ++n_) \
            acc[(mh)*4 + i_][n_] = __builtin_amdgcn_mfma_f32_16x16x32_bf16(af[i_], bfr[n_], acc[(mh)*4 + i_][n_], 0, 0, 0); \
    __builtin_amdgcn_s_setprio(0); \
    __builtin_amdgcn_sched_barrier(0); \
    VM_STMT; \
    __builtin_amdgcn_s_barrier(); \
    __builtin_amdgcn_sched_barrier(0); \
} while (0)

template<int HAS_BIAS, int OUT_BF16>
__global__ __launch_bounds__(512, 2)
void gemm5_k(const ushort* __restrict__ A, const ushort* __restrict__ Bt,
             const float* __restrict__ bias, void* __restrict__ Cv,
             int N, int K)
{
    __shared__ ushort AsF[32768];   // 64KB: [2 dbuf][2 kh][256][32]
    __shared__ ushort BsF[32768];   // 64KB
    const int tid = threadIdx.x;
    const int l = tid & 63;
    const int w = tid >> 6;
    const int wr = w >> 2;             // 0..1
    const int wc = w & 3;              // 0..3

    // XCD/L2-aware bijective remap: each XCD owns a y-band (gy/8 rows of
    // 256), traversed in 4x4 block sub-tiles. Requires gx%4==0, gy%8==0.
    const int gx = gridDim.x;
    const int lin = blockIdx.y * gx + blockIdx.x;
    const int xcd = lin & 7;
    const int idx = lin >> 3;          // 0 .. gx*(gy/8)-1
    const int hb = gridDim.y >> 3;     // y-band height (blocks)
    const int sxc = gx >> 2;           // 4-wide x sub-tiles
    const int g4 = idx >> 4;
    const int li = idx & 15;
    const int bx = (g4 % sxc) * 4 + (li & 3);
    const int by = xcd * hb + (g4 / sxc) * 4 + (li >> 2);
    const int bm = by * 256;
    const int bn = bx * 256;
    const int NT = K >> 6;             // K-tiles of 64

    // staging: chunk c=j*8+w covers rows c*16..+15; lane: row l>>2,
    // physical colbyte (l&3)*16; pre-swizzled global col:
    const int srow = w * 16 + (l >> 2);
    const int scol = ((l & 3) ^ ((l >> 3) & 3)) * 8;
    const ushort* Ag = A  + (size_t)(bm + srow) * K + scol;
    const ushort* Bg = Bt + (size_t)(bn + srow) * K + scol;
    const size_t row128 = (size_t)128 * K;
    const int lchunk = w * 512;        // ushort offset of wave's j=0 chunk

    // frag ds_read: row ...+lr, logical k-off (l>>4)*8; swizzled (lane-constant):
    const int lr = l & 15;
    const int fb = (((l >> 4) ^ ((l >> 1) & 3)) * 8);

    f32x4 acc[8][4];
#pragma unroll
    for (int i = 0; i < 8; ++i)
#pragma unroll
        for (int n = 0; n < 4; ++n)
            acc[i][n] = (f32x4){0.f, 0.f, 0.f, 0.f};
    short8 bfr[4];                      // B frags persist across mh phases

    // prologue: stage t0 fully (4 half-stages = 8 loads); land A.kh0,B.kh0
    STAGE_A(0, 0); STAGE_B(0, 0);
    STAGE_A(0, 1); STAGE_B(0, 1);
    VMC(4);
    __builtin_amdgcn_s_barrier();
    __builtin_amdgcn_sched_barrier(0);

    for (int t = 0; t < NT; ++t) {
        const int d = t & 1;
        PHASE5(d, 0, 0, 1, { if (t + 1 < NT) STAGE_A(t + 1, 0); }, {});
        PHASE5(d, 0, 1, 0, { if (t + 1 < NT) STAGE_B(t + 1, 0); },
               { if (t == NT - 1) VMC(0); else VMC(4); });
        PHASE5(d, 1, 0, 1, { if (t + 1 < NT) STAGE_A(t + 1, 1); }, {});
        PHASE5(d, 1, 1, 0, { if (t + 1 < NT) STAGE_B(t + 1, 1); },
               { if (t != NT - 1) VMC(4); });
    }

    // epilogue: C/D layout col=lane&15, row=(lane>>4)*4+reg
    const int cr = (l >> 4) * 4;
    const int cc = l & 15;
    float bv[4];
#pragma unroll
    for (int n = 0; n < 4; ++n)
        bv[n] = HAS_BIAS ? bias[bn + wc * 64 + n * 16 + cc] : 0.f;
#pragma unroll
    for (int m = 0; m < 8; ++m) {
#pragma unroll
        for (int n = 0; n < 4; ++n) {
            const int col = bn + wc * 64 + n * 16 + cc;
#pragma unroll
            for (int r = 0; r < 4; ++r) {
                const int row = bm + wr * 128 + m * 16 + cr + r;
                float v = acc[m][n][r] + bv[n];
                if (OUT_BF16) ((ushort*)Cv)[(size_t)row * N + col] = f2bf(v);
                else          ((float*)Cv)[(size_t)row * N + col] = v;
            }
        }
    }
}

// ---------------- per-(b,t) attention ----------------
// qkv: [16384][3072] (q|k|v per timestep), pbuf: [16384][1024]
__global__ __launch_bounds__(256)
void attn_k(const ushort* __restrict__ qkv, const ushort* __restrict__ pbuf,
            const float* __restrict__ ubias, const float* __restrict__ vbias,
            const int* __restrict__ masks, ushort* __restrict__ ctx)
{
    __shared__ float qu[16][65];   // q(m)+u_bias
    __shared__ float kk[16][65];
    __shared__ float vv[16][65];
    __shared__ float qv[16][65];   // q(mp)+v_bias (rel-shift source)
    __shared__ float pp[16][65];
    __shared__ float at[16][16];

    const int m  = blockIdx.x;         // b2*T + t2
    const int b2 = m >> 11;
    const int t2 = m & 2047;
    const int f  = m + 8;              // rel-shift: flat block index + B
    const int bs = f / 2049;
    const int ts = f - bs * 2049;
    const bool haspos = (ts != 0);     // ts==0 -> zero pad row
    const int mp = bs * 2048 + ts - 1;

    const int tid = threadIdx.x;
    const int e = tid * 4;
    const int h = e >> 6;
    const int d = e & 63;

    {
        const ushort* base = qkv + (size_t)m * 3072;
        ushort4 a = *(const ushort4*)(base + e);
        ushort4 b = *(const ushort4*)(base + 1024 + e);
        ushort4 c = *(const ushort4*)(base + 2048 + e);
        float4 uu = *(const float4*)(ubias + e);
        qu[h][d + 0] = bf2f(a.x) + uu.x;
        qu[h][d + 1] = bf2f(a.y) + uu.y;
        qu[h][d + 2] = bf2f(a.z) + uu.z;
        qu[h][d + 3] = bf2f(a.w) + uu.w;
        kk[h][d + 0] = bf2f(b.x);
        kk[h][d + 1] = bf2f(b.y);
        kk[h][d + 2] = bf2f(b.z);
        kk[h][d + 3] = bf2f(b.w);
        vv[h][d + 0] = bf2f(c.x);
        vv[h][d + 1] = bf2f(c.y);
        vv[h][d + 2] = bf2f(c.z);
        vv[h][d + 3] = bf2f(c.w);
        if (haspos) {
            ushort4 qq = *(const ushort4*)(qkv + (size_t)mp * 3072 + e);
            ushort4 pq = *(const ushort4*)(pbuf + (size_t)mp * 1024 + e);
            float4 vv4 = *(const float4*)(vbias + e);
            qv[h][d + 0] = bf2f(qq.x) + vv4.x;
            qv[h][d + 1] = bf2f(qq.y) + vv4.y;
            qv[h][d + 2] = bf2f(qq.z) + vv4.z;
            qv[h][d + 3] = bf2f(qq.w) + vv4.w;
            pp[h][d + 0] = bf2f(pq.x);
            pp[h][d + 1] = bf2f(pq.y);
            pp[h][d + 2] = bf2f(pq.z);
            pp[h][d + 3] = bf2f(pq.w);
        } else {
            qv[h][d + 0] = 0.f; qv[h][d + 1] = 0.f; qv[h][d + 2] = 0.f; qv[h][d + 3] = 0.f;
            pp[h][d + 0] = 0.f; pp[h][d + 1] = 0.f; pp[h][d + 2] = 0.f; pp[h][d + 3] = 0.f;
        }
    }
    __syncthreads();

    const int sh = tid >> 4;   // score row h
    const int sk = tid & 15;   // score col k'
    float cs = 0.f, ps = 0.f;
#pragma unroll 8
    for (int dd = 0; dd < 64; ++dd) {
        cs += qu[sh][dd] * kk[sk][dd];
        ps += qv[sh][dd] * pp[sk][dd];
    }
    float score = (cs + ps) * 0.03125f;   // /sqrt(1024)
    score = (masks[m] != 0) ? score : 1e-9f;

    // softmax over sk within contiguous 16-lane groups
    float mx = score;
#pragma unroll
    for (int o = 8; o; o >>= 1) mx = fmaxf(mx, __shfl_xor(mx, o, 64));
    float ex = __expf(score - mx);
    float sum = ex;
#pragma unroll
    for (int o = 8; o; o >>= 1) sum += __shfl_xor(sum, o, 64);
    at[sh][sk] = ex / sum;
    __syncthreads();

    // ctx[h][d] = sum_k at[h][k]*v[k][d]; write in output-GEMM layout:
    // row = b2*2048 + h*128 + t2/16, col = (t2%16)*64 + d
#pragma unroll
    for (int j = 0; j < 4; ++j) {
        const int idx = tid + j * 256;
        const int hh = idx >> 6;
        const int dd2 = idx & 63;
        float s = 0.f;
#pragma unroll
        for (int k2 = 0; k2 < 16; ++k2)
            s += at[hh][k2] * vv[k2][dd2];
        const size_t orow = (size_t)b2 * 2048 + hh * 128 + (t2 >> 4);
        ctx[orow * 1024 + (t2 & 15) * 64 + dd2] = f2bf(s);
    }
}

extern "C" void kernel_launch(void* const* d_in, const int* in_sizes, int n_in,
                              void* d_out, int out_size, void* d_ws, size_t ws_size,
                              hipStream_t stream)
{
    (void)in_sizes; (void)n_in; (void)out_size; (void)ws_size;
    const float* inputs = (const float*)d_in[0];
    const float* pos    = (const float*)d_in[1];
    const int*   masks  = (const int*)d_in[2];
    const float* Wq = (const float*)d_in[3];
    const float* bq = (const float*)d_in[4];
    const float* Wk = (const float*)d_in[5];
    const float* bk = (const float*)d_in[6];
    const float* Wv = (const float*)d_in[7];
    const float* bv = (const float*)d_in[8];
    const float* Wp = (const float*)d_in[9];
    const float* Wo = (const float*)d_in[10];
    const float* bo = (const float*)d_in[11];
    const float* ub = (const float*)d_in[12];
    const float* vb = (const float*)d_in[13];

    // ws layout:
    //   [0,10MB)      WqT|WkT|WvT|WpT|WoT  (bf16 [N][K], contiguous -> fused QKV B)
    //   [10MB,+64KB)  biascat (f32[3072])
    //   S1 (32MB): pos_bf16 -> inputs_bf16 -> ctx   (sequential reuse)
    //   S2 (32MB): pbuf  (pos @ Wp, bf16)
    //   S3 (96MB): qkv   ([16384][3072] bf16)
    char* ws = (char*)d_ws;
    const size_t WT_SZ = (size_t)1024 * 1024 * 2;
    ushort* WqT = (ushort*)(ws);
    ushort* WkT = (ushort*)(ws + 1 * WT_SZ);
    ushort* WvT = (ushort*)(ws + 2 * WT_SZ);
    ushort* WpT = (ushort*)(ws + 3 * WT_SZ);
    ushort* WoT = (ushort*)(ws + 4 * WT_SZ);
    float*  biascat = (float*)(ws + 5 * WT_SZ);
    char* bufs = ws + 5 * WT_SZ + 65536;
    const size_t S_SZ = (size_t)16384 * 1024 * 2;       // 32MB
    ushort* S1 = (ushort*)(bufs);
    ushort* S2 = (ushort*)(bufs + S_SZ);
    ushort* S3 = (ushort*)(bufs + 2 * S_SZ);            // 96MB

    dim3 blk(256);
    dim3 tgrid(32, 32);

    // weights + biases
    transpose_convert_k<<<tgrid, blk, 0, stream>>>(Wq, WqT, 1024, 1024);
    transpose_convert_k<<<tgrid, blk, 0, stream>>>(Wk, WkT, 1024, 1024);
    transpose_convert_k<<<tgrid, blk, 0, stream>>>(Wv, WvT, 1024, 1024);
    transpose_convert_k<<<tgrid, blk, 0, stream>>>(Wp, WpT, 1024, 1024);
    transpose_convert_k<<<tgrid, blk, 0, stream>>>(Wo, WoT, 1024, 1024);
    bias_concat_k<<<dim3(12), blk, 0, stream>>>(bq, bk, bv, biascat);

    // pos -> bf16 (S1); P-GEMM -> S2
    conv_bf16_k<<<dim3(8192), blk, 0, stream>>>(pos, S1);
    gemm5_k<0, 1><<<dim3(4, 64), dim3(512), 0, stream>>>(S1, WpT, nullptr, S2, 1024, 1024);

    // inputs -> bf16 (S1); fused QKV GEMM -> S3
    conv_bf16_k<<<dim3(8192), blk, 0, stream>>>(inputs, S1);
    gemm5_k<1, 1><<<dim3(12, 64), dim3(512), 0, stream>>>(S1, WqT, biascat, S3, 3072, 1024);

    // attention -> ctx (S1, overwrites inputs_bf16)
    attn_k<<<dim3(16384), blk, 0, stream>>>(S3, S2, ub, vb, masks, S1);

    // out = ctx @ Wo + bo  (f32)
    gemm5_k<1, 0><<<dim3(4, 64), dim3(512), 0, stream>>>(S1, WoT, bo, (float*)d_out, 1024, 1024);
}